// Round 1
// baseline (983.262 us; speedup 1.0000x reference)
//
#include <hip/hip_runtime.h>
#include <hip/hip_cooperative_groups.h>
#include <math.h>

namespace cg = cooperative_groups;

// Problem constants (fixed by the reference)
#define NND 50000   // nodes
#define LNP 50048   // padded rows: 782 * 64, guard-free gemm
#define NED 600000  // edges
#define CD  128     // channels (in = hid = 128)
#define NG  64      // graphs
#define NBLK 196    // ceil(NND/256) scan blocks
#define GROWS 64    // rows per fused tile
#define GGRID (LNP / GROWS)   // 782 tiles

typedef short s8v  __attribute__((ext_vector_type(8)));   // 8 bf16 (raw bits) = 4 VGPRs
typedef float f4v  __attribute__((ext_vector_type(4)));   // MFMA accumulator
typedef float f2v  __attribute__((ext_vector_type(2)));
typedef unsigned short u16x8 __attribute__((ext_vector_type(8)));

static __device__ __forceinline__ unsigned short f2bf(float f) {
  union { float f; unsigned u; } v; v.f = f;
  unsigned r = v.u + 0x7fffu + ((v.u >> 16) & 1u);   // round-to-nearest-even
  return (unsigned short)(r >> 16);
}
// truncating f32->bf16: EXACT when the value is fp8-representable
static __device__ __forceinline__ unsigned short f2bf_t(float f) {
  union { float f; unsigned u; } v; v.f = f;
  return (unsigned short)(v.u >> 16);
}
// 4 floats -> 4 packed OCP e4m3 bytes (HW RNE+sat)
static __device__ __forceinline__ unsigned f2fp8x4(float a, float b, float c, float d) {
  int r = __builtin_amdgcn_cvt_pk_fp8_f32(a, b, 0, false);
  r = __builtin_amdgcn_cvt_pk_fp8_f32(c, d, r, true);
  return (unsigned)r;
}
// 8 packed fp8 bytes -> 8 bf16 (exact: e4m3 subset of bf16)
static __device__ __forceinline__ s8v fp8x8_to_bf16(uint2 v) {
  f2v c0 = __builtin_amdgcn_cvt_pk_f32_fp8(v.x, false);
  f2v c1 = __builtin_amdgcn_cvt_pk_f32_fp8(v.x, true);
  f2v c2 = __builtin_amdgcn_cvt_pk_f32_fp8(v.y, false);
  f2v c3 = __builtin_amdgcn_cvt_pk_f32_fp8(v.y, true);
  union { u16x8 u; s8v s; } o;
  o.u[0] = f2bf_t(c0.x); o.u[1] = f2bf_t(c0.y);
  o.u[2] = f2bf_t(c1.x); o.u[3] = f2bf_t(c1.y);
  o.u[4] = f2bf_t(c2.x); o.u[5] = f2bf_t(c2.y);
  o.u[6] = f2bf_t(c3.x); o.u[7] = f2bf_t(c3.y);
  return o.s;
}
// async global->LDS, 16B per lane (wave-uniform LDS base + lane*16)
static __device__ __forceinline__ void g2lds8(const unsigned char* g, unsigned char* l) {
  __builtin_amdgcn_global_load_lds(
      (const __attribute__((address_space(1))) unsigned*)g,
      (__attribute__((address_space(3))) unsigned*)l, 16, 0, 0);
}

// ---- 3-stage grid scan of cnt[NND] -> offs (exclusive), cur, offs[NND]=total ----
__global__ __launch_bounds__(256) void bsum_k(const int* __restrict__ cnt,
                                              int* __restrict__ bsum) {
  __shared__ int s[256];
  int i = blockIdx.x * 256 + threadIdx.x;
  s[threadIdx.x] = (i < NND) ? cnt[i] : 0;
  __syncthreads();
  for (int off = 128; off > 0; off >>= 1) {
    if (threadIdx.x < off) s[threadIdx.x] += s[threadIdx.x + off];
    __syncthreads();
  }
  if (threadIdx.x == 0) bsum[blockIdx.x] = s[0];
}

// also folds in graph-boundary binary search (batch is SORTED): gb[g]=lower_bound(g)
__global__ __launch_bounds__(256) void bscan_k(const int* __restrict__ bsum,
                                               int* __restrict__ boff,
                                               int* __restrict__ offs,
                                               const int* __restrict__ batch,
                                               int* __restrict__ gb) {
  __shared__ int s[256];
  int t = threadIdx.x;
  if (t <= NG) {
    int lo = 0, hi = NND;
    while (lo < hi) {
      int mid = (lo + hi) >> 1;
      if (batch[mid] < t) lo = mid + 1; else hi = mid;
    }
    gb[t] = lo;
  }
  s[t] = (t < NBLK) ? bsum[t] : 0;
  __syncthreads();
  for (int off = 1; off < 256; off <<= 1) {   // inclusive Hillis-Steele
    int v = (t >= off) ? s[t - off] : 0;
    __syncthreads();
    s[t] += v;
    __syncthreads();
  }
  if (t < NBLK) boff[t] = (t == 0) ? 0 : s[t - 1];
  if (t == NBLK - 1) offs[NND] = s[t];        // grand total
}

__global__ __launch_bounds__(256) void escan_k(const int* __restrict__ cnt,
                                               const int* __restrict__ boff,
                                               int* __restrict__ offs,
                                               int* __restrict__ cur) {
  __shared__ int s[256];
  int i = blockIdx.x * 256 + threadIdx.x;
  int t = threadIdx.x;
  int v = (i < NND) ? cnt[i] : 0;
  s[t] = v;
  __syncthreads();
  for (int off = 1; off < 256; off <<= 1) {   // inclusive Hillis-Steele
    int u = (t >= off) ? s[t - off] : 0;
    __syncthreads();
    s[t] += u;
    __syncthreads();
  }
  if (i < NND) {
    int excl = s[t] - v + boff[blockIdx.x];   // inclusive - self = exclusive
    offs[i] = excl;
    cur[i]  = excl;
  }
}

// ---- CSR fill: csr[pos] = src for edges grouped by dst ----
__global__ void fill_k(const int* __restrict__ src, const int* __restrict__ dst,
                       int* __restrict__ cur, int* __restrict__ csr) {
  int e = blockIdx.x * blockDim.x + threadIdx.x;
  if (e >= NED) return;
  int d = dst[e];
  int pos = atomicAdd(&cur[d], 1);
  csr[pos] = src[e];
}

// ---- merged preamble: x->fp8 (range 0), weight transposes (range 1),
//      degree count for CSR (range 2, atomics hidden under streaming) ----
struct WPtrs { const float* w[8]; unsigned short* wt[8]; };
__global__ void prep_k(const float* __restrict__ x, unsigned* __restrict__ x8,
                       WPtrs p, const int* __restrict__ dst, int* __restrict__ cnt) {
  int t = blockIdx.x * blockDim.x + threadIdx.x;
  if (t < NND * 32) {                 // one float4 chunk per thread
    float4 v = reinterpret_cast<const float4*>(x)[t];
    x8[t] = f2fp8x4(v.x, v.y, v.z, v.w);
  } else {
    int u = t - NND * 32;             // 8*16384 weight elements
    if (u < 8 * CD * CD) {
      int m = u >> 14, r = u & (CD * CD - 1);
      int n = r >> 7, k = r & 127;
      p.wt[m][r] = f2bf(p.w[m][k * CD + n]);
    } else {
      int e = u - 8 * CD * CD;        // NED degree counts
      if (e < NED) atomicAdd(&cnt[dst[e]], 1);
    }
  }
}

// ---- one fused SAGE tile (64 rows). Same structure as prior sage_k, plus:
//  * abuf XOR-swizzled BOTH sides (16B slot ^= row&7)      -> kills 16-way conflict
//  * x8buf: pre-swizzled DMA *source* chunk, linear LDS dest, swizzled read
//    (rule #21: global_load_lds dest must stay linear)      -> kills 16-way conflict
//  * B fragments loaded AFTER the gather loop: gather-loop VGPR pressure -64,
//    no spill risk under the 128-VGPR cap of __launch_bounds__(256,4)
struct WT8 { const unsigned short* w[8]; };
struct BP4 { const float* b[4]; };

static __device__ __forceinline__ void sage_tile(
    int tile,
    const unsigned* __restrict__ xq,
    const int* __restrict__ csr, const int* __restrict__ offs,
    const unsigned short* __restrict__ WlT, const unsigned short* __restrict__ WrT,
    const float* __restrict__ bias, unsigned char* __restrict__ h8,
    const int* __restrict__ batch, float* __restrict__ pooled,
    unsigned short* abuf, unsigned char* x8buf, int* sB) {
  const int tid  = threadIdx.x;
  const int wave = tid >> 6;
  const int lane = tid & 63;
  const int quad = lane >> 4;
  const int l16  = lane & 15;
  const size_t rbase = (size_t)tile * GROWS;

  // root fp8 DMA first (fire-and-forget): 512 slots of 16B, source chunk
  // pre-swizzled so LDS slot s holds global chunk (s&7)^(row&7)
  {
    const unsigned char* xg = (const unsigned char*)xq;
#pragma unroll
    for (int j = 0; j < 2; ++j) {
      const int s = j * 256 + tid;
      const int row = s >> 3;
      const int c = (s & 7) ^ (row & 7);
      g2lds8(xg + (rbase + row) * CD + c * 16, &x8buf[(size_t)s * 16]);
    }
  }

  // batch ids for pooling (tiny)
  if (pooled && tid < GROWS) {
    size_t row = rbase + tid;
    sB[tid] = (row < NND) ? batch[row] : -1;
  }

  // Gather phase: 32 teams x 8 lanes; team handles rows rbase + team*2 + i
  {
    const int team = tid >> 3;
    const int tl   = tid & 7;                  // owns channels [tl*16, tl*16+16)
    const unsigned* base = xq + tl * 4;        // 4 u32 = 16 fp8 channels
    for (int i = 0; i < 2; ++i) {
      const int rl = team * 2 + i;
      const size_t row = rbase + rl;
      u16x8 o0 = {}, o1 = {};
      if (row < NND) {
        const int e0 = offs[row], e1 = offs[row + 1];
        f2v a[8] = {};
        int e = e0;
        for (; e + 4 <= e1; e += 4) {
          int s[4];
#pragma unroll
          for (int j = 0; j < 4; ++j) s[j] = csr[e + j];
          uint4 v[4];
#pragma unroll
          for (int j = 0; j < 4; ++j)
            v[j] = *reinterpret_cast<const uint4*>(base + (size_t)s[j] * 32);
#pragma unroll
          for (int j = 0; j < 4; ++j) {
            a[0] += __builtin_amdgcn_cvt_pk_f32_fp8(v[j].x, false);
            a[1] += __builtin_amdgcn_cvt_pk_f32_fp8(v[j].x, true);
            a[2] += __builtin_amdgcn_cvt_pk_f32_fp8(v[j].y, false);
            a[3] += __builtin_amdgcn_cvt_pk_f32_fp8(v[j].y, true);
            a[4] += __builtin_amdgcn_cvt_pk_f32_fp8(v[j].z, false);
            a[5] += __builtin_amdgcn_cvt_pk_f32_fp8(v[j].z, true);
            a[6] += __builtin_amdgcn_cvt_pk_f32_fp8(v[j].w, false);
            a[7] += __builtin_amdgcn_cvt_pk_f32_fp8(v[j].w, true);
          }
        }
        for (; e < e1; ++e) {
          uint4 v = *reinterpret_cast<const uint4*>(base + (size_t)csr[e] * 32);
          a[0] += __builtin_amdgcn_cvt_pk_f32_fp8(v.x, false);
          a[1] += __builtin_amdgcn_cvt_pk_f32_fp8(v.x, true);
          a[2] += __builtin_amdgcn_cvt_pk_f32_fp8(v.y, false);
          a[3] += __builtin_amdgcn_cvt_pk_f32_fp8(v.y, true);
          a[4] += __builtin_amdgcn_cvt_pk_f32_fp8(v.z, false);
          a[5] += __builtin_amdgcn_cvt_pk_f32_fp8(v.z, true);
          a[6] += __builtin_amdgcn_cvt_pk_f32_fp8(v.w, false);
          a[7] += __builtin_amdgcn_cvt_pk_f32_fp8(v.w, true);
        }
        const float invd = 1.0f / fmaxf((float)(e1 - e0), 1.0f);
#pragma unroll
        for (int c = 0; c < 4; ++c) {
          o0[2 * c]     = f2bf(a[c].x * invd);
          o0[2 * c + 1] = f2bf(a[c].y * invd);
          o1[2 * c]     = f2bf(a[4 + c].x * invd);
          o1[2 * c + 1] = f2bf(a[4 + c].y * invd);
        }
      }
      // swizzled store: 16B slot index ^= (row & 7)
      char* ab = (char*)(abuf + rl * CD);
      const int swr = rl & 7;
      *reinterpret_cast<u16x8*>(ab + ((((tl << 1))     ^ swr) << 4)) = o0;
      *reinterpret_cast<u16x8*>(ab + ((((tl << 1) | 1) ^ swr) << 4)) = o1;
    }
  }

  // B fragments AFTER gather (weights L2-hot; latency hidden under the barrier)
  s8v bL[2][4], bR[2][4];
#pragma unroll
  for (int nt = 0; nt < 2; ++nt) {
    const int n = wave * 32 + nt * 16 + l16;
#pragma unroll
    for (int kk = 0; kk < 4; ++kk) {
      size_t woff = (size_t)n * CD + kk * 32 + quad * 8;
      bL[nt][kk] = *reinterpret_cast<const s8v*>(WlT + woff);
      bR[nt][kk] = *reinterpret_cast<const s8v*>(WrT + woff);
    }
  }
  const float bv0 = bias[wave * 32 + l16];
  const float bv1 = bias[wave * 32 + 16 + l16];

  __syncthreads();   // drains DMA (vmcnt) + LDS writes + barrier

  const bool fast = pooled && (rbase + GROWS <= NND) && (sB[0] == sB[GROWS - 1]);
  const int c0 = wave * 32 + l16;
  float p0 = 0.f, p1 = 0.f;

  // MFMA phase (swizzled LDS reads, 2-way max bank aliasing = free)
#pragma unroll
  for (int rt = 0; rt < GROWS / 16; ++rt) {
    const int row = rt * 16 + l16;
    const int sw  = row & 7;
    const char* arow = (const char*)(abuf + row * CD);
    const char* xrow = (const char*)(x8buf + row * CD);
    f4v acc0 = {}, acc1 = {};
#pragma unroll
    for (int kk = 0; kk < 4; ++kk) {
      s8v aA = *reinterpret_cast<const s8v*>(arow + (((quad + kk * 4) ^ sw) << 4));
      uint2 xv = *reinterpret_cast<const uint2*>(
          xrow + ((((quad >> 1) + kk * 2) ^ sw) << 4) + ((quad & 1) << 3));
      s8v aX = fp8x8_to_bf16(xv);
      acc0 = __builtin_amdgcn_mfma_f32_16x16x32_bf16(aA, bL[0][kk], acc0, 0, 0, 0);
      acc0 = __builtin_amdgcn_mfma_f32_16x16x32_bf16(aX, bR[0][kk], acc0, 0, 0, 0);
      acc1 = __builtin_amdgcn_mfma_f32_16x16x32_bf16(aA, bL[1][kk], acc1, 0, 0, 0);
      acc1 = __builtin_amdgcn_mfma_f32_16x16x32_bf16(aX, bR[1][kk], acc1, 0, 0, 0);
    }
    const size_t row0 = rbase + rt * 16 + quad * 4;
#pragma unroll
    for (int r = 0; r < 4; ++r) {
      const size_t orow = row0 + r;
      float v0 = fmaxf(acc0[r] + bv0, 0.0f);
      float v1 = fmaxf(acc1[r] + bv1, 0.0f);
      if (h8) {
        int q0 = __builtin_amdgcn_cvt_pk_fp8_f32(v0, v0, 0, false);
        int q1 = __builtin_amdgcn_cvt_pk_fp8_f32(v1, v1, 0, false);
        h8[orow * CD + c0]      = (unsigned char)q0;
        h8[orow * CD + c0 + 16] = (unsigned char)q1;
      }
      if (pooled) {
        if (fast) {
          p0 += v0; p1 += v1;
        } else {
          int g = sB[rt * 16 + quad * 4 + r];
          if (g >= 0) {
            atomicAdd(&pooled[g * CD + c0], v0);
            atomicAdd(&pooled[g * CD + c0 + 16], v1);
          }
        }
      }
    }
  }

  if (fast) {   // butterfly column-reduce across quads, one atomic pair per col
    p0 += __shfl_xor(p0, 16, 64);
    p0 += __shfl_xor(p0, 32, 64);
    p1 += __shfl_xor(p1, 16, 64);
    p1 += __shfl_xor(p1, 32, 64);
    if (quad == 0) {
      const int g = sB[0];
      atomicAdd(&pooled[g * CD + c0], p0);
      atomicAdd(&pooled[g * CD + c0 + 16], p1);
    }
  }

  __syncthreads();   // protect LDS (abuf/x8buf/sB) reuse by the next tile/layer
}

// ---- cooperative fused kernel: 4 SAGE layers + classifier, grid.sync between.
// Each layer writes a FRESH fp8 table (no reader can hold a stale-clean line of
// its input); __threadfence (agent release/acquire -> wbl2/inv) around each
// grid.sync handles cross-XCD dirty-line visibility.
__global__ __launch_bounds__(256, 4) void sage_coop_k(
    const unsigned* q0, unsigned char* q1, unsigned char* q2, unsigned char* q3,
    const int* __restrict__ csr, const int* __restrict__ offs,
    WT8 wt, BP4 bp,
    const int* __restrict__ batch, float* __restrict__ pooled,
    const int* __restrict__ gb, const float* __restrict__ Wc,
    const float* __restrict__ bc, float* __restrict__ out) {
  cg::grid_group grid = cg::this_grid();
  __shared__ unsigned short abuf[GROWS * CD];   // 16 KB aggregated means (bf16)
  __shared__ unsigned char  x8buf[GROWS * CD];  // 8 KB root features (fp8 DMA)
  __shared__ int sB[GROWS];

#pragma unroll 1
  for (int l = 0; l < 4; ++l) {
    // constant-index selects (no runtime-indexed arrays -> no scratch, rule #20)
    const unsigned* qin = (l == 0) ? q0
                        : (l == 1) ? (const unsigned*)q1
                        : (l == 2) ? (const unsigned*)q2
                                   : (const unsigned*)q3;
    unsigned char* qout = (l == 0) ? q1 : (l == 1) ? q2 : (l == 2) ? q3 : nullptr;
    const unsigned short* Wl = (l == 0) ? wt.w[0] : (l == 1) ? wt.w[2]
                             : (l == 2) ? wt.w[4] : wt.w[6];
    const unsigned short* Wr = (l == 0) ? wt.w[1] : (l == 1) ? wt.w[3]
                             : (l == 2) ? wt.w[5] : wt.w[7];
    const float* bs = (l == 0) ? bp.b[0] : (l == 1) ? bp.b[1]
                    : (l == 2) ? bp.b[2] : bp.b[3];
    float* pl = (l == 3) ? pooled : nullptr;

    for (int t = blockIdx.x; t < GGRID; t += gridDim.x)
      sage_tile(t, qin, csr, offs, Wl, Wr, bs, qout, batch, pl, abuf, x8buf, sB);

    __threadfence();   // agent release: write back dirty L2 lines (cross-XCD)
    grid.sync();
    __threadfence();   // agent acquire: invalidate stale-clean lines
  }

  // classifier by block 0: out[g] = sigmoid(dot(pooled[g]/cnt, Wc) + bc)
  if (blockIdx.x == 0) {
    const int wv = threadIdx.x >> 6, ln = threadIdx.x & 63;
    for (int g = wv; g < NG; g += 4) {
      float a0 = __hip_atomic_load(&pooled[g * CD + ln],
                                   __ATOMIC_RELAXED, __HIP_MEMORY_SCOPE_AGENT);
      float a1 = __hip_atomic_load(&pooled[g * CD + 64 + ln],
                                   __ATOMIC_RELAXED, __HIP_MEMORY_SCOPE_AGENT);
      float part = a0 * Wc[ln] + a1 * Wc[64 + ln];
#pragma unroll
      for (int off = 32; off > 0; off >>= 1) part += __shfl_down(part, off, 64);
      if (ln == 0) {
        float cnt = (float)(gb[g + 1] - gb[g]);
        float z = part / fmaxf(cnt, 1.0f) + bc[0];
        out[g] = 1.0f / (1.0f + expf(-z));
      }
    }
  }
}

extern "C" void kernel_launch(void* const* d_in, const int* in_sizes, int n_in,
                              void* d_out, int out_size, void* d_ws, size_t ws_size,
                              hipStream_t stream) {
  const float* x   = (const float*)d_in[0];
  const int*   ei  = (const int*)d_in[1];
  const int*   src = ei;             // edge_index[0]
  const int*   dst = ei + NED;       // edge_index[1]
  // d_in[2] = edge_weight: unused by the reference
  const int*   batch = (const int*)d_in[3];
  const float* Wc = (const float*)d_in[16];
  const float* bc = (const float*)d_in[17];
  float* out = (float*)d_out;

  char* w = (char*)d_ws;
  auto alloc = [&](size_t bytes) {
    char* p = w; w += (bytes + 255) & ~(size_t)255; return p;
  };
  // cnti + pooled first and contiguous: one memset covers both
  int* cnti = (int*)alloc(NND * 4);
  float* pooled = (float*)alloc(NG * CD * 4);
  size_t zspan = (size_t)(w - (char*)cnti);
  int* offs = (int*)alloc((NND + 1) * 4);
  int* cur  = (int*)alloc(NND * 4);
  int* csr  = (int*)alloc((size_t)NED * 4);
  int* gb   = (int*)alloc((NG + 1) * 4);
  int* bsum = (int*)alloc(256 * 4);
  int* boff = (int*)alloc(256 * 4);
  // four fp8 feature tables: input + one fresh output per layer 0-2
  unsigned char* x8a = (unsigned char*)alloc((size_t)LNP * CD);
  unsigned char* x8b = (unsigned char*)alloc((size_t)LNP * CD);
  unsigned char* x8c = (unsigned char*)alloc((size_t)LNP * CD);
  unsigned char* x8d = (unsigned char*)alloc((size_t)LNP * CD);
  WPtrs wp;
  for (int i = 0; i < 4; ++i) {
    wp.w[2 * i]     = (const float*)d_in[4 + 3 * i];      // Wl{i+1}
    wp.w[2 * i + 1] = (const float*)d_in[5 + 3 * i];      // Wr{i+1}
  }
  for (int i = 0; i < 8; ++i) wp.wt[i] = (unsigned short*)alloc(CD * CD * 2);
  const float* bs[4] = {(const float*)d_in[6],  (const float*)d_in[9],
                        (const float*)d_in[12], (const float*)d_in[15]};

  hipMemsetAsync(cnti, 0, zspan, stream);

  // preamble: fp8 convert + weight transposes + degree count in ONE kernel
  prep_k<<<(NND * 32 + 8 * CD * CD + NED + 255) / 256, 256, 0, stream>>>(
      x, (unsigned*)x8a, wp, dst, cnti);

  // CSR build (per call; inputs are restored before every timed launch)
  bsum_k<<<NBLK, 256, 0, stream>>>(cnti, bsum);
  bscan_k<<<1, 256, 0, stream>>>(bsum, boff, offs, batch, gb);
  escan_k<<<NBLK, 256, 0, stream>>>(cnti, boff, offs, cur);
  fill_k<<<(NED + 255) / 256, 256, 0, stream>>>(src, dst, cur, csr);

  // cooperative fused 4-layer + classifier. Grid clamped to co-residency.
  static int coopGrid = 0;
  if (coopGrid == 0) {
    int occ = 0;
    hipOccupancyMaxActiveBlocksPerMultiprocessor(&occ, sage_coop_k, 256, 0);
    if (occ < 1) occ = 1;
    long cap = (long)occ * 256;                // 256 CUs on MI355X
    coopGrid = (int)((cap < GGRID) ? cap : GGRID);
  }
  WT8 wt8; for (int i = 0; i < 8; ++i) wt8.w[i] = wp.wt[i];
  BP4 bp4; for (int i = 0; i < 4; ++i) bp4.b[i] = bs[i];
  const unsigned* a_q0 = (const unsigned*)x8a;
  unsigned char* a_q1 = x8b;
  unsigned char* a_q2 = x8c;
  unsigned char* a_q3 = x8d;
  const int* a_csr = csr;
  const int* a_offs = offs;
  const int* a_batch = batch;
  float* a_pooled = pooled;
  const int* a_gb = gb;
  const float* a_Wc = Wc;
  const float* a_bc = bc;
  float* a_out = out;
  void* args[] = {&a_q0, &a_q1, &a_q2, &a_q3, &a_csr, &a_offs, &wt8, &bp4,
                  &a_batch, &a_pooled, &a_gb, &a_Wc, &a_bc, &a_out};
  hipLaunchCooperativeKernel(sage_coop_k, dim3(coopGrid), dim3(256), args, 0, stream);
}

// Round 2
// 348.426 us; speedup vs baseline: 2.8220x; 2.8220x over previous
//
#include <hip/hip_runtime.h>
#include <math.h>

// Problem constants (fixed by the reference)
#define NND 50000   // nodes
#define LNP 50048   // padded rows: 782 * 64, guard-free gemm
#define NED 600000  // edges
#define CD  128     // channels (in = hid = 128)
#define NG  64      // graphs
#define NBLK 196    // ceil(NND/256) scan blocks
#define GROWS 64    // rows per fused block
#define GGRID (LNP / GROWS)   // 782 tiles

typedef short s8v  __attribute__((ext_vector_type(8)));   // 8 bf16 (raw bits) = 4 VGPRs
typedef float f4v  __attribute__((ext_vector_type(4)));   // MFMA accumulator
typedef float f2v  __attribute__((ext_vector_type(2)));
typedef unsigned short u16x8 __attribute__((ext_vector_type(8)));

static __device__ __forceinline__ unsigned short f2bf(float f) {
  union { float f; unsigned u; } v; v.f = f;
  unsigned r = v.u + 0x7fffu + ((v.u >> 16) & 1u);   // round-to-nearest-even
  return (unsigned short)(r >> 16);
}
// truncating f32->bf16: EXACT when the value is fp8-representable
static __device__ __forceinline__ unsigned short f2bf_t(float f) {
  union { float f; unsigned u; } v; v.f = f;
  return (unsigned short)(v.u >> 16);
}
// 4 floats -> 4 packed OCP e4m3 bytes (HW RNE+sat)
static __device__ __forceinline__ unsigned f2fp8x4(float a, float b, float c, float d) {
  int r = __builtin_amdgcn_cvt_pk_fp8_f32(a, b, 0, false);
  r = __builtin_amdgcn_cvt_pk_fp8_f32(c, d, r, true);
  return (unsigned)r;
}
// 8 packed fp8 bytes -> 8 bf16 (exact: e4m3 subset of bf16)
static __device__ __forceinline__ s8v fp8x8_to_bf16(uint2 v) {
  f2v c0 = __builtin_amdgcn_cvt_pk_f32_fp8(v.x, false);
  f2v c1 = __builtin_amdgcn_cvt_pk_f32_fp8(v.x, true);
  f2v c2 = __builtin_amdgcn_cvt_pk_f32_fp8(v.y, false);
  f2v c3 = __builtin_amdgcn_cvt_pk_f32_fp8(v.y, true);
  union { u16x8 u; s8v s; } o;
  o.u[0] = f2bf_t(c0.x); o.u[1] = f2bf_t(c0.y);
  o.u[2] = f2bf_t(c1.x); o.u[3] = f2bf_t(c1.y);
  o.u[4] = f2bf_t(c2.x); o.u[5] = f2bf_t(c2.y);
  o.u[6] = f2bf_t(c3.x); o.u[7] = f2bf_t(c3.y);
  return o.s;
}
// async global->LDS, 16B per lane (wave-uniform LDS base + lane*16)
static __device__ __forceinline__ void g2lds8(const unsigned char* g, unsigned char* l) {
  __builtin_amdgcn_global_load_lds(
      (const __attribute__((address_space(1))) unsigned*)g,
      (__attribute__((address_space(3))) unsigned*)l, 16, 0, 0);
}

// ---- 3-stage grid scan of cnt[NND] -> offs (exclusive), cur, offs[NND]=total ----
__global__ __launch_bounds__(256) void bsum_k(const int* __restrict__ cnt,
                                              int* __restrict__ bsum) {
  __shared__ int s[256];
  int i = blockIdx.x * 256 + threadIdx.x;
  s[threadIdx.x] = (i < NND) ? cnt[i] : 0;
  __syncthreads();
  for (int off = 128; off > 0; off >>= 1) {
    if (threadIdx.x < off) s[threadIdx.x] += s[threadIdx.x + off];
    __syncthreads();
  }
  if (threadIdx.x == 0) bsum[blockIdx.x] = s[0];
}

// also folds in graph-boundary binary search (batch is SORTED): gb[g]=lower_bound(g)
__global__ __launch_bounds__(256) void bscan_k(const int* __restrict__ bsum,
                                               int* __restrict__ boff,
                                               int* __restrict__ offs,
                                               const int* __restrict__ batch,
                                               int* __restrict__ gb) {
  __shared__ int s[256];
  int t = threadIdx.x;
  if (t <= NG) {
    int lo = 0, hi = NND;
    while (lo < hi) {
      int mid = (lo + hi) >> 1;
      if (batch[mid] < t) lo = mid + 1; else hi = mid;
    }
    gb[t] = lo;
  }
  s[t] = (t < NBLK) ? bsum[t] : 0;
  __syncthreads();
  for (int off = 1; off < 256; off <<= 1) {   // inclusive Hillis-Steele
    int v = (t >= off) ? s[t - off] : 0;
    __syncthreads();
    s[t] += v;
    __syncthreads();
  }
  if (t < NBLK) boff[t] = (t == 0) ? 0 : s[t - 1];
  if (t == NBLK - 1) offs[NND] = s[t];        // grand total
}

__global__ __launch_bounds__(256) void escan_k(const int* __restrict__ cnt,
                                               const int* __restrict__ boff,
                                               int* __restrict__ offs,
                                               int* __restrict__ cur) {
  __shared__ int s[256];
  int i = blockIdx.x * 256 + threadIdx.x;
  int t = threadIdx.x;
  int v = (i < NND) ? cnt[i] : 0;
  s[t] = v;
  __syncthreads();
  for (int off = 1; off < 256; off <<= 1) {   // inclusive Hillis-Steele
    int u = (t >= off) ? s[t - off] : 0;
    __syncthreads();
    s[t] += u;
    __syncthreads();
  }
  if (i < NND) {
    int excl = s[t] - v + boff[blockIdx.x];   // inclusive - self = exclusive
    offs[i] = excl;
    cur[i]  = excl;
  }
}

// ---- CSR fill: csr[pos] = src for edges grouped by dst ----
__global__ void fill_k(const int* __restrict__ src, const int* __restrict__ dst,
                       int* __restrict__ cur, int* __restrict__ csr) {
  int e = blockIdx.x * blockDim.x + threadIdx.x;
  if (e >= NED) return;
  int d = dst[e];
  int pos = atomicAdd(&cur[d], 1);
  csr[pos] = src[e];
}

// ---- merged preamble: x->fp8 (range 0), weight transposes (range 1),
//      degree count for CSR (range 2, atomics hidden under streaming) ----
struct WPtrs { const float* w[8]; unsigned short* wt[8]; };
__global__ void prep_k(const float* __restrict__ x, unsigned* __restrict__ x8,
                       WPtrs p, const int* __restrict__ dst, int* __restrict__ cnt) {
  int t = blockIdx.x * blockDim.x + threadIdx.x;
  if (t < NND * 32) {                 // one float4 chunk per thread
    float4 v = reinterpret_cast<const float4*>(x)[t];
    x8[t] = f2fp8x4(v.x, v.y, v.z, v.w);
  } else {
    int u = t - NND * 32;             // 8*16384 weight elements
    if (u < 8 * CD * CD) {
      int m = u >> 14, r = u & (CD * CD - 1);
      int n = r >> 7, k = r & 127;
      p.wt[m][r] = f2bf(p.w[m][k * CD + n]);
    } else {
      int e = u - 8 * CD * CD;        // NED degree counts
      if (e < NED) atomicAdd(&cnt[dst[e]], 1);
    }
  }
}

// ---- FUSED SAGE layer (split-launch version, R2):
//  * abuf XOR-swizzled BOTH sides (16B slot ^= row&7)   -> kills 16-way read conflict
//  * x8buf: pre-swizzled DMA *source* chunk, linear LDS dest, swizzled read
//  * B fragments loaded AFTER the gather loop (gather VGPR pressure -64)
//  * gather main loop 8-deep unrolled (2x outstanding loads vs R0's 4-deep)
//  * layer 3: pooling epilogue + done-counter-fused classifier (final_k removed)
__global__ __launch_bounds__(256, 4) void sage_k(
    const unsigned* __restrict__ xq,
    const int* __restrict__ csr, const int* __restrict__ offs,
    const unsigned short* __restrict__ WlT, const unsigned short* __restrict__ WrT,
    const float* __restrict__ bias, unsigned char* __restrict__ h8,
    const int* __restrict__ batch, float* __restrict__ pooled,
    int* __restrict__ done, const int* __restrict__ gb,
    const float* __restrict__ Wc, const float* __restrict__ bc,
    float* __restrict__ out) {
  __shared__ unsigned short abuf[GROWS * CD];   // 16 KB aggregated means (bf16)
  __shared__ unsigned char  x8buf[GROWS * CD];  // 8 KB root features (fp8 DMA)
  __shared__ int sB[GROWS];                     // graph ids of the block's rows
  __shared__ int slast;                         // am I the last block? (layer 3)

  const int tid  = threadIdx.x;
  const int wave = tid >> 6;
  const int lane = tid & 63;
  const int quad = lane >> 4;
  const int l16  = lane & 15;
  const size_t rbase = (size_t)blockIdx.x * GROWS;

  // root fp8 DMA first (fire-and-forget): 512 slots of 16B; source chunk
  // pre-swizzled so LDS slot s holds global chunk (s&7)^(row&7)
  {
    const unsigned char* xg = (const unsigned char*)xq;
#pragma unroll
    for (int j = 0; j < 2; ++j) {
      const int s = j * 256 + tid;
      const int row = s >> 3;
      const int c = (s & 7) ^ (row & 7);
      g2lds8(xg + (rbase + row) * CD + c * 16, &x8buf[(size_t)s * 16]);
    }
  }

  // batch ids for pooling (tiny)
  if (pooled && tid < GROWS) {
    size_t row = rbase + tid;
    sB[tid] = (row < NND) ? batch[row] : -1;
  }

  // Gather phase: 32 teams x 8 lanes; team handles rows rbase + team*2 + i
  {
    const int team = tid >> 3;
    const int tl   = tid & 7;                  // owns channels [tl*16, tl*16+16)
    const unsigned* base = xq + tl * 4;        // 4 u32 = 16 fp8 channels
    for (int i = 0; i < 2; ++i) {
      const int rl = team * 2 + i;
      const size_t row = rbase + rl;
      u16x8 o0 = {}, o1 = {};
      if (row < NND) {
        const int e0 = offs[row], e1 = offs[row + 1];
        f2v a[8] = {};
        int e = e0;
        for (; e + 8 <= e1; e += 8) {          // 8-deep: 8 loads in flight
          int s[8];
#pragma unroll
          for (int j = 0; j < 8; ++j) s[j] = csr[e + j];
          uint4 v[8];
#pragma unroll
          for (int j = 0; j < 8; ++j)
            v[j] = *reinterpret_cast<const uint4*>(base + (size_t)s[j] * 32);
#pragma unroll
          for (int j = 0; j < 8; ++j) {
            a[0] += __builtin_amdgcn_cvt_pk_f32_fp8(v[j].x, false);
            a[1] += __builtin_amdgcn_cvt_pk_f32_fp8(v[j].x, true);
            a[2] += __builtin_amdgcn_cvt_pk_f32_fp8(v[j].y, false);
            a[3] += __builtin_amdgcn_cvt_pk_f32_fp8(v[j].y, true);
            a[4] += __builtin_amdgcn_cvt_pk_f32_fp8(v[j].z, false);
            a[5] += __builtin_amdgcn_cvt_pk_f32_fp8(v[j].z, true);
            a[6] += __builtin_amdgcn_cvt_pk_f32_fp8(v[j].w, false);
            a[7] += __builtin_amdgcn_cvt_pk_f32_fp8(v[j].w, true);
          }
        }
        for (; e + 4 <= e1; e += 4) {          // 4-deep tail
          int s[4];
#pragma unroll
          for (int j = 0; j < 4; ++j) s[j] = csr[e + j];
          uint4 v[4];
#pragma unroll
          for (int j = 0; j < 4; ++j)
            v[j] = *reinterpret_cast<const uint4*>(base + (size_t)s[j] * 32);
#pragma unroll
          for (int j = 0; j < 4; ++j) {
            a[0] += __builtin_amdgcn_cvt_pk_f32_fp8(v[j].x, false);
            a[1] += __builtin_amdgcn_cvt_pk_f32_fp8(v[j].x, true);
            a[2] += __builtin_amdgcn_cvt_pk_f32_fp8(v[j].y, false);
            a[3] += __builtin_amdgcn_cvt_pk_f32_fp8(v[j].y, true);
            a[4] += __builtin_amdgcn_cvt_pk_f32_fp8(v[j].z, false);
            a[5] += __builtin_amdgcn_cvt_pk_f32_fp8(v[j].z, true);
            a[6] += __builtin_amdgcn_cvt_pk_f32_fp8(v[j].w, false);
            a[7] += __builtin_amdgcn_cvt_pk_f32_fp8(v[j].w, true);
          }
        }
        for (; e < e1; ++e) {
          uint4 v = *reinterpret_cast<const uint4*>(base + (size_t)csr[e] * 32);
          a[0] += __builtin_amdgcn_cvt_pk_f32_fp8(v.x, false);
          a[1] += __builtin_amdgcn_cvt_pk_f32_fp8(v.x, true);
          a[2] += __builtin_amdgcn_cvt_pk_f32_fp8(v.y, false);
          a[3] += __builtin_amdgcn_cvt_pk_f32_fp8(v.y, true);
          a[4] += __builtin_amdgcn_cvt_pk_f32_fp8(v.z, false);
          a[5] += __builtin_amdgcn_cvt_pk_f32_fp8(v.z, true);
          a[6] += __builtin_amdgcn_cvt_pk_f32_fp8(v.w, false);
          a[7] += __builtin_amdgcn_cvt_pk_f32_fp8(v.w, true);
        }
        const float invd = 1.0f / fmaxf((float)(e1 - e0), 1.0f);
#pragma unroll
        for (int c = 0; c < 4; ++c) {
          o0[2 * c]     = f2bf(a[c].x * invd);
          o0[2 * c + 1] = f2bf(a[c].y * invd);
          o1[2 * c]     = f2bf(a[4 + c].x * invd);
          o1[2 * c + 1] = f2bf(a[4 + c].y * invd);
        }
      }
      // swizzled store: 16B slot index ^= (row & 7)
      char* ab = (char*)(abuf + rl * CD);
      const int swr = rl & 7;
      *reinterpret_cast<u16x8*>(ab + ((((tl << 1))     ^ swr) << 4)) = o0;
      *reinterpret_cast<u16x8*>(ab + ((((tl << 1) | 1) ^ swr) << 4)) = o1;
    }
  }

  // B fragments AFTER gather (weights L2-hot; latency hidden under the barrier)
  s8v bL[2][4], bR[2][4];
#pragma unroll
  for (int nt = 0; nt < 2; ++nt) {
    const int n = wave * 32 + nt * 16 + l16;
#pragma unroll
    for (int kk = 0; kk < 4; ++kk) {
      size_t woff = (size_t)n * CD + kk * 32 + quad * 8;
      bL[nt][kk] = *reinterpret_cast<const s8v*>(WlT + woff);
      bR[nt][kk] = *reinterpret_cast<const s8v*>(WrT + woff);
    }
  }
  const float bv0 = bias[wave * 32 + l16];
  const float bv1 = bias[wave * 32 + 16 + l16];

  __syncthreads();   // drains DMA (vmcnt) + LDS writes + barrier

  const bool fast = pooled && (rbase + GROWS <= NND) && (sB[0] == sB[GROWS - 1]);
  const int c0 = wave * 32 + l16;
  float p0 = 0.f, p1 = 0.f;

  // MFMA phase (swizzled LDS reads, 2-way max bank aliasing = free)
#pragma unroll
  for (int rt = 0; rt < GROWS / 16; ++rt) {
    const int row = rt * 16 + l16;
    const int sw  = row & 7;
    const char* arow = (const char*)(abuf + row * CD);
    const char* xrow = (const char*)(x8buf + row * CD);
    f4v acc0 = {}, acc1 = {};
#pragma unroll
    for (int kk = 0; kk < 4; ++kk) {
      s8v aA = *reinterpret_cast<const s8v*>(arow + (((quad + kk * 4) ^ sw) << 4));
      uint2 xv = *reinterpret_cast<const uint2*>(
          xrow + ((((quad >> 1) + kk * 2) ^ sw) << 4) + ((quad & 1) << 3));
      s8v aX = fp8x8_to_bf16(xv);
      acc0 = __builtin_amdgcn_mfma_f32_16x16x32_bf16(aA, bL[0][kk], acc0, 0, 0, 0);
      acc0 = __builtin_amdgcn_mfma_f32_16x16x32_bf16(aX, bR[0][kk], acc0, 0, 0, 0);
      acc1 = __builtin_amdgcn_mfma_f32_16x16x32_bf16(aA, bL[1][kk], acc1, 0, 0, 0);
      acc1 = __builtin_amdgcn_mfma_f32_16x16x32_bf16(aX, bR[1][kk], acc1, 0, 0, 0);
    }
    const size_t row0 = rbase + rt * 16 + quad * 4;
#pragma unroll
    for (int r = 0; r < 4; ++r) {
      const size_t orow = row0 + r;
      float v0 = fmaxf(acc0[r] + bv0, 0.0f);
      float v1 = fmaxf(acc1[r] + bv1, 0.0f);
      if (h8) {
        int q0 = __builtin_amdgcn_cvt_pk_fp8_f32(v0, v0, 0, false);
        int q1 = __builtin_amdgcn_cvt_pk_fp8_f32(v1, v1, 0, false);
        h8[orow * CD + c0]      = (unsigned char)q0;
        h8[orow * CD + c0 + 16] = (unsigned char)q1;
      }
      if (pooled) {
        if (fast) {
          p0 += v0; p1 += v1;
        } else {
          int g = sB[rt * 16 + quad * 4 + r];
          if (g >= 0) {
            atomicAdd(&pooled[g * CD + c0], v0);
            atomicAdd(&pooled[g * CD + c0 + 16], v1);
          }
        }
      }
    }
  }

  if (!pooled) return;

  if (fast) {   // butterfly column-reduce across quads, one atomic pair per col
    p0 += __shfl_xor(p0, 16, 64);
    p0 += __shfl_xor(p0, 32, 64);
    p1 += __shfl_xor(p1, 16, 64);
    p1 += __shfl_xor(p1, 32, 64);
    if (quad == 0) {
      const int g = sB[0];
      atomicAdd(&pooled[g * CD + c0], p0);
      atomicAdd(&pooled[g * CD + c0 + 16], p1);
    }
  }

  // ---- fused classifier: last block to retire computes out[g] ----
  __threadfence();   // release: my pooled atomics visible before counter bump
  if (tid == 0) {
    int prev = __hip_atomic_fetch_add(done, 1, __ATOMIC_ACQ_REL,
                                      __HIP_MEMORY_SCOPE_AGENT);
    slast = (prev == GGRID - 1) ? 1 : 0;
  }
  __syncthreads();
  if (slast) {
    const int wv = tid >> 6, ln = tid & 63;
    for (int g = wv; g < NG; g += 4) {
      float a0 = __hip_atomic_load(&pooled[g * CD + ln],
                                   __ATOMIC_RELAXED, __HIP_MEMORY_SCOPE_AGENT);
      float a1 = __hip_atomic_load(&pooled[g * CD + 64 + ln],
                                   __ATOMIC_RELAXED, __HIP_MEMORY_SCOPE_AGENT);
      float part = a0 * Wc[ln] + a1 * Wc[64 + ln];
#pragma unroll
      for (int off = 32; off > 0; off >>= 1) part += __shfl_down(part, off, 64);
      if (ln == 0) {
        float cnt = (float)(gb[g + 1] - gb[g]);
        float z = part / fmaxf(cnt, 1.0f) + bc[0];
        out[g] = 1.0f / (1.0f + expf(-z));
      }
    }
  }
}

extern "C" void kernel_launch(void* const* d_in, const int* in_sizes, int n_in,
                              void* d_out, int out_size, void* d_ws, size_t ws_size,
                              hipStream_t stream) {
  const float* x   = (const float*)d_in[0];
  const int*   ei  = (const int*)d_in[1];
  const int*   src = ei;             // edge_index[0]
  const int*   dst = ei + NED;       // edge_index[1]
  // d_in[2] = edge_weight: unused by the reference
  const int*   batch = (const int*)d_in[3];
  const float* Wc = (const float*)d_in[16];
  const float* bc = (const float*)d_in[17];
  float* out = (float*)d_out;

  char* w = (char*)d_ws;
  auto alloc = [&](size_t bytes) {
    char* p = w; w += (bytes + 255) & ~(size_t)255; return p;
  };
  // cnti + pooled + done first and contiguous: one memset covers all three
  int* cnti = (int*)alloc(NND * 4);
  float* pooled = (float*)alloc(NG * CD * 4);
  int* done = (int*)alloc(4);
  size_t zspan = (size_t)(w - (char*)cnti);
  int* offs = (int*)alloc((NND + 1) * 4);
  int* cur  = (int*)alloc(NND * 4);
  int* csr  = (int*)alloc((size_t)NED * 4);
  int* gb   = (int*)alloc((NG + 1) * 4);
  int* bsum = (int*)alloc(256 * 4);
  int* boff = (int*)alloc(256 * 4);
  unsigned char* x8a = (unsigned char*)alloc((size_t)LNP * CD);
  unsigned char* x8b = (unsigned char*)alloc((size_t)LNP * CD);
  WPtrs wp;
  for (int i = 0; i < 4; ++i) {
    wp.w[2 * i]     = (const float*)d_in[4 + 3 * i];      // Wl{i+1}
    wp.w[2 * i + 1] = (const float*)d_in[5 + 3 * i];      // Wr{i+1}
  }
  for (int i = 0; i < 8; ++i) wp.wt[i] = (unsigned short*)alloc(CD * CD * 2);
  const float* bs[4] = {(const float*)d_in[6],  (const float*)d_in[9],
                        (const float*)d_in[12], (const float*)d_in[15]};

  hipMemsetAsync(cnti, 0, zspan, stream);

  // preamble: fp8 convert + weight transposes + degree count in ONE kernel
  prep_k<<<(NND * 32 + 8 * CD * CD + NED + 255) / 256, 256, 0, stream>>>(
      x, (unsigned*)x8a, wp, dst, cnti);

  // CSR build (per call; inputs are restored before every timed launch)
  bsum_k<<<NBLK, 256, 0, stream>>>(cnti, bsum);
  bscan_k<<<1, 256, 0, stream>>>(bsum, boff, offs, batch, gb);
  escan_k<<<NBLK, 256, 0, stream>>>(cnti, boff, offs, cur);
  fill_k<<<(NED + 255) / 256, 256, 0, stream>>>(src, dst, cur, csr);

  unsigned char* qcur = x8a;
  unsigned char* qnxt = x8b;
  for (int l = 0; l < 4; ++l) {
    if (l < 3) {
      sage_k<<<GGRID, 256, 0, stream>>>((const unsigned*)qcur, csr, offs,
                                        wp.wt[2 * l], wp.wt[2 * l + 1], bs[l],
                                        qnxt, batch, nullptr,
                                        done, gb, Wc, bc, out);
      unsigned char* q = qcur; qcur = qnxt; qnxt = q;
    } else {
      // last layer: no feature output — pooling + classifier fused in epilogue
      sage_k<<<GGRID, 256, 0, stream>>>((const unsigned*)qcur, csr, offs,
                                        wp.wt[2 * l], wp.wt[2 * l + 1], bs[l],
                                        nullptr, batch, pooled,
                                        done, gb, Wc, bc, out);
    }
  }
}

// Round 3
// 345.561 us; speedup vs baseline: 2.8454x; 1.0083x over previous
//
#include <hip/hip_runtime.h>
#include <math.h>

// Problem constants (fixed by the reference)
#define NND 50000   // nodes
#define LNP 50048   // padded rows: 782 * 64, guard-free gemm
#define NED 600000  // edges
#define CD  128     // channels (in = hid = 128)
#define NG  64      // graphs
#define NBLK 196    // ceil(NND/256) scan blocks
#define GROWS 64    // rows per fused block
#define GGRID (LNP / GROWS)   // 782 tiles

typedef short s8v  __attribute__((ext_vector_type(8)));   // 8 bf16 (raw bits) = 4 VGPRs
typedef float f4v  __attribute__((ext_vector_type(4)));   // MFMA accumulator
typedef float f2v  __attribute__((ext_vector_type(2)));
typedef unsigned short u16x8 __attribute__((ext_vector_type(8)));

static __device__ __forceinline__ unsigned short f2bf(float f) {
  union { float f; unsigned u; } v; v.f = f;
  unsigned r = v.u + 0x7fffu + ((v.u >> 16) & 1u);   // round-to-nearest-even
  return (unsigned short)(r >> 16);
}
// truncating f32->bf16: EXACT when the value is fp8-representable
static __device__ __forceinline__ unsigned short f2bf_t(float f) {
  union { float f; unsigned u; } v; v.f = f;
  return (unsigned short)(v.u >> 16);
}
// 4 floats -> 4 packed OCP e4m3 bytes (HW RNE+sat)
static __device__ __forceinline__ unsigned f2fp8x4(float a, float b, float c, float d) {
  int r = __builtin_amdgcn_cvt_pk_fp8_f32(a, b, 0, false);
  r = __builtin_amdgcn_cvt_pk_fp8_f32(c, d, r, true);
  return (unsigned)r;
}
// 8 packed fp8 bytes -> 8 bf16 (exact: e4m3 subset of bf16)
static __device__ __forceinline__ s8v fp8x8_to_bf16(uint2 v) {
  f2v c0 = __builtin_amdgcn_cvt_pk_f32_fp8(v.x, false);
  f2v c1 = __builtin_amdgcn_cvt_pk_f32_fp8(v.x, true);
  f2v c2 = __builtin_amdgcn_cvt_pk_f32_fp8(v.y, false);
  f2v c3 = __builtin_amdgcn_cvt_pk_f32_fp8(v.y, true);
  union { u16x8 u; s8v s; } o;
  o.u[0] = f2bf_t(c0.x); o.u[1] = f2bf_t(c0.y);
  o.u[2] = f2bf_t(c1.x); o.u[3] = f2bf_t(c1.y);
  o.u[4] = f2bf_t(c2.x); o.u[5] = f2bf_t(c2.y);
  o.u[6] = f2bf_t(c3.x); o.u[7] = f2bf_t(c3.y);
  return o.s;
}
// async global->LDS, 16B per lane (wave-uniform LDS base + lane*16)
static __device__ __forceinline__ void g2lds8(const unsigned char* g, unsigned char* l) {
  __builtin_amdgcn_global_load_lds(
      (const __attribute__((address_space(1))) unsigned*)g,
      (__attribute__((address_space(3))) unsigned*)l, 16, 0, 0);
}

// ---- 3-stage grid scan of cnt[NND] -> offs (exclusive), cur, offs[NND]=total ----
__global__ __launch_bounds__(256) void bsum_k(const int* __restrict__ cnt,
                                              int* __restrict__ bsum) {
  __shared__ int s[256];
  int i = blockIdx.x * 256 + threadIdx.x;
  s[threadIdx.x] = (i < NND) ? cnt[i] : 0;
  __syncthreads();
  for (int off = 128; off > 0; off >>= 1) {
    if (threadIdx.x < off) s[threadIdx.x] += s[threadIdx.x + off];
    __syncthreads();
  }
  if (threadIdx.x == 0) bsum[blockIdx.x] = s[0];
}

// also folds in graph-boundary binary search (batch is SORTED): gb[g]=lower_bound(g)
__global__ __launch_bounds__(256) void bscan_k(const int* __restrict__ bsum,
                                               int* __restrict__ boff,
                                               int* __restrict__ offs,
                                               const int* __restrict__ batch,
                                               int* __restrict__ gb) {
  __shared__ int s[256];
  int t = threadIdx.x;
  if (t <= NG) {
    int lo = 0, hi = NND;
    while (lo < hi) {
      int mid = (lo + hi) >> 1;
      if (batch[mid] < t) lo = mid + 1; else hi = mid;
    }
    gb[t] = lo;
  }
  s[t] = (t < NBLK) ? bsum[t] : 0;
  __syncthreads();
  for (int off = 1; off < 256; off <<= 1) {   // inclusive Hillis-Steele
    int v = (t >= off) ? s[t - off] : 0;
    __syncthreads();
    s[t] += v;
    __syncthreads();
  }
  if (t < NBLK) boff[t] = (t == 0) ? 0 : s[t - 1];
  if (t == NBLK - 1) offs[NND] = s[t];        // grand total
}

__global__ __launch_bounds__(256) void escan_k(const int* __restrict__ cnt,
                                               const int* __restrict__ boff,
                                               int* __restrict__ offs,
                                               int* __restrict__ cur) {
  __shared__ int s[256];
  int i = blockIdx.x * 256 + threadIdx.x;
  int t = threadIdx.x;
  int v = (i < NND) ? cnt[i] : 0;
  s[t] = v;
  __syncthreads();
  for (int off = 1; off < 256; off <<= 1) {   // inclusive Hillis-Steele
    int u = (t >= off) ? s[t - off] : 0;
    __syncthreads();
    s[t] += u;
    __syncthreads();
  }
  if (i < NND) {
    int excl = s[t] - v + boff[blockIdx.x];   // inclusive - self = exclusive
    offs[i] = excl;
    cur[i]  = excl;
  }
}

// ---- CSR fill: csr[pos] = src for edges grouped by dst ----
__global__ void fill_k(const int* __restrict__ src, const int* __restrict__ dst,
                       int* __restrict__ cur, int* __restrict__ csr) {
  int e = blockIdx.x * blockDim.x + threadIdx.x;
  if (e >= NED) return;
  int d = dst[e];
  int pos = atomicAdd(&cur[d], 1);
  csr[pos] = src[e];
}

// ---- merged preamble: x->fp8 (range 0), weight transposes (range 1),
//      degree count for CSR (range 2, atomics hidden under streaming) ----
struct WPtrs { const float* w[8]; unsigned short* wt[8]; };
__global__ void prep_k(const float* __restrict__ x, unsigned* __restrict__ x8,
                       WPtrs p, const int* __restrict__ dst, int* __restrict__ cnt) {
  int t = blockIdx.x * blockDim.x + threadIdx.x;
  if (t < NND * 32) {                 // one float4 chunk per thread
    float4 v = reinterpret_cast<const float4*>(x)[t];
    x8[t] = f2fp8x4(v.x, v.y, v.z, v.w);
  } else {
    int u = t - NND * 32;             // 8*16384 weight elements
    if (u < 8 * CD * CD) {
      int m = u >> 14, r = u & (CD * CD - 1);
      int n = r >> 7, k = r & 127;
      p.wt[m][r] = f2bf(p.w[m][k * CD + n]);
    } else {
      int e = u - 8 * CD * CD;        // NED degree counts
      if (e < NED) atomicAdd(&cnt[dst[e]], 1);
    }
  }
}

// ---- FUSED SAGE layer (R3):
//  * gather = explicitly software-pipelined: idx 1 batch ahead, features 2
//    batches in flight, sched_barrier(0) pins loads above consumes so the
//    scheduler cannot serialize them to chase a 64-VGPR occupancy band
//    (R2 post-mortem: VGPR=56 => ~1 load in flight => 97us/dispatch)
//  * abuf XOR-swizzled BOTH sides (16B slot ^= row&7)  -> kills 16-way conflict
//  * x8buf: pre-swizzled DMA *source* chunk, linear LDS dest, swizzled read
//  * B fragments after gather (kept out of the gather's register pressure)
//  * layer 3: pooling epilogue + done-counter-fused classifier
__global__ __launch_bounds__(256, 4) void sage_k(
    const unsigned* __restrict__ xq,
    const int* __restrict__ csr, const int* __restrict__ offs,
    const unsigned short* __restrict__ WlT, const unsigned short* __restrict__ WrT,
    const float* __restrict__ bias, unsigned char* __restrict__ h8,
    const int* __restrict__ batch, float* __restrict__ pooled,
    int* __restrict__ done, const int* __restrict__ gb,
    const float* __restrict__ Wc, const float* __restrict__ bc,
    float* __restrict__ out) {
  __shared__ unsigned short abuf[GROWS * CD];   // 16 KB aggregated means (bf16)
  __shared__ unsigned char  x8buf[GROWS * CD];  // 8 KB root features (fp8 DMA)
  __shared__ int sB[GROWS];                     // graph ids of the block's rows
  __shared__ int slast;                         // am I the last block? (layer 3)

  const int tid  = threadIdx.x;
  const int wave = tid >> 6;
  const int lane = tid & 63;
  const int quad = lane >> 4;
  const int l16  = lane & 15;
  const size_t rbase = (size_t)blockIdx.x * GROWS;

  // root fp8 DMA first (fire-and-forget): 512 slots of 16B; source chunk
  // pre-swizzled so LDS slot s holds global chunk (s&7)^(row&7)
  {
    const unsigned char* xg = (const unsigned char*)xq;
#pragma unroll
    for (int j = 0; j < 2; ++j) {
      const int s = j * 256 + tid;
      const int row = s >> 3;
      const int c = (s & 7) ^ (row & 7);
      g2lds8(xg + (rbase + row) * CD + c * 16, &x8buf[(size_t)s * 16]);
    }
  }

  // batch ids for pooling (tiny)
  if (pooled && tid < GROWS) {
    size_t row = rbase + tid;
    sB[tid] = (row < NND) ? batch[row] : -1;
  }

  // Gather phase: 32 teams x 8 lanes; team handles rows rbase + team*2 + i
  {
    const int team = tid >> 3;
    const int tl   = tid & 7;                  // owns channels [tl*16, tl*16+16)
    const unsigned* base = xq + tl * 4;        // 4 u32 = 16 fp8 channels
    for (int i = 0; i < 2; ++i) {
      const int rl = team * 2 + i;
      const size_t row = rbase + rl;
      u16x8 o0 = {}, o1 = {};
      if (row < NND) {
        const int e0 = offs[row], e1 = offs[row + 1];
        f2v a[8] = {};
        auto acc1 = [&](uint4 v) {
          a[0] += __builtin_amdgcn_cvt_pk_f32_fp8(v.x, false);
          a[1] += __builtin_amdgcn_cvt_pk_f32_fp8(v.x, true);
          a[2] += __builtin_amdgcn_cvt_pk_f32_fp8(v.y, false);
          a[3] += __builtin_amdgcn_cvt_pk_f32_fp8(v.y, true);
          a[4] += __builtin_amdgcn_cvt_pk_f32_fp8(v.z, false);
          a[5] += __builtin_amdgcn_cvt_pk_f32_fp8(v.z, true);
          a[6] += __builtin_amdgcn_cvt_pk_f32_fp8(v.w, false);
          a[7] += __builtin_amdgcn_cvt_pk_f32_fp8(v.w, true);
        };
        auto LD4 = [&](int s) {
          return *reinterpret_cast<const uint4*>(base + (size_t)s * 32);
        };
        int e = e0;
        const int nb = (e1 - e0) >> 2;         // 4-edge batches
        if (nb >= 2) {
          // prologue: batch0 features in flight, batch1 indices ready
          int i0 = csr[e], i1 = csr[e + 1], i2 = csr[e + 2], i3 = csr[e + 3];
          uint4 f0 = LD4(i0), f1 = LD4(i1), f2 = LD4(i2), f3 = LD4(i3);
          int j0 = csr[e + 4], j1 = csr[e + 5], j2 = csr[e + 6], j3 = csr[e + 7];
          e += 8;
          for (int b = 2; b < nb; ++b, e += 4) {
            // issue next-batch features + next-next indices FIRST
            uint4 g0 = LD4(j0), g1 = LD4(j1), g2 = LD4(j2), g3 = LD4(j3);
            int k0 = csr[e], k1 = csr[e + 1], k2 = csr[e + 2], k3 = csr[e + 3];
            __builtin_amdgcn_sched_barrier(0);   // pin: loads stay above
            acc1(f0); acc1(f1); acc1(f2); acc1(f3);
            f0 = g0; f1 = g1; f2 = g2; f3 = g3;
            j0 = k0; j1 = k1; j2 = k2; j3 = k3;
          }
          // drain: batch nb-2 in flight, batch nb-1 indices ready
          uint4 g0 = LD4(j0), g1 = LD4(j1), g2 = LD4(j2), g3 = LD4(j3);
          __builtin_amdgcn_sched_barrier(0);
          acc1(f0); acc1(f1); acc1(f2); acc1(f3);
          acc1(g0); acc1(g1); acc1(g2); acc1(g3);
        } else if (nb == 1) {
          int i0 = csr[e], i1 = csr[e + 1], i2 = csr[e + 2], i3 = csr[e + 3];
          uint4 f0 = LD4(i0), f1 = LD4(i1), f2 = LD4(i2), f3 = LD4(i3);
          acc1(f0); acc1(f1); acc1(f2); acc1(f3);
          e += 4;
        }
        for (; e < e1; ++e) acc1(LD4(csr[e]));
        const float invd = 1.0f / fmaxf((float)(e1 - e0), 1.0f);
#pragma unroll
        for (int c = 0; c < 4; ++c) {
          o0[2 * c]     = f2bf(a[c].x * invd);
          o0[2 * c + 1] = f2bf(a[c].y * invd);
          o1[2 * c]     = f2bf(a[4 + c].x * invd);
          o1[2 * c + 1] = f2bf(a[4 + c].y * invd);
        }
      }
      // swizzled store: 16B slot index ^= (row & 7)
      char* ab = (char*)(abuf + rl * CD);
      const int swr = rl & 7;
      *reinterpret_cast<u16x8*>(ab + ((((tl << 1))     ^ swr) << 4)) = o0;
      *reinterpret_cast<u16x8*>(ab + ((((tl << 1) | 1) ^ swr) << 4)) = o1;
    }
  }

  // B fragments AFTER gather (weights L2-hot; latency hidden under the barrier)
  s8v bL[2][4], bR[2][4];
#pragma unroll
  for (int nt = 0; nt < 2; ++nt) {
    const int n = wave * 32 + nt * 16 + l16;
#pragma unroll
    for (int kk = 0; kk < 4; ++kk) {
      size_t woff = (size_t)n * CD + kk * 32 + quad * 8;
      bL[nt][kk] = *reinterpret_cast<const s8v*>(WlT + woff);
      bR[nt][kk] = *reinterpret_cast<const s8v*>(WrT + woff);
    }
  }
  const float bv0 = bias[wave * 32 + l16];
  const float bv1 = bias[wave * 32 + 16 + l16];

  __syncthreads();   // drains DMA (vmcnt) + LDS writes + barrier

  const bool fast = pooled && (rbase + GROWS <= NND) && (sB[0] == sB[GROWS - 1]);
  const int c0 = wave * 32 + l16;
  float p0 = 0.f, p1 = 0.f;

  // MFMA phase (swizzled LDS reads, 2-way max bank aliasing = free)
#pragma unroll
  for (int rt = 0; rt < GROWS / 16; ++rt) {
    const int row = rt * 16 + l16;
    const int sw  = row & 7;
    const char* arow = (const char*)(abuf + row * CD);
    const char* xrow = (const char*)(x8buf + row * CD);
    f4v acc0 = {}, acc1 = {};
#pragma unroll
    for (int kk = 0; kk < 4; ++kk) {
      s8v aA = *reinterpret_cast<const s8v*>(arow + (((quad + kk * 4) ^ sw) << 4));
      uint2 xv = *reinterpret_cast<const uint2*>(
          xrow + ((((quad >> 1) + kk * 2) ^ sw) << 4) + ((quad & 1) << 3));
      s8v aX = fp8x8_to_bf16(xv);
      acc0 = __builtin_amdgcn_mfma_f32_16x16x32_bf16(aA, bL[0][kk], acc0, 0, 0, 0);
      acc0 = __builtin_amdgcn_mfma_f32_16x16x32_bf16(aX, bR[0][kk], acc0, 0, 0, 0);
      acc1 = __builtin_amdgcn_mfma_f32_16x16x32_bf16(aA, bL[1][kk], acc1, 0, 0, 0);
      acc1 = __builtin_amdgcn_mfma_f32_16x16x32_bf16(aX, bR[1][kk], acc1, 0, 0, 0);
    }
    const size_t row0 = rbase + rt * 16 + quad * 4;
#pragma unroll
    for (int r = 0; r < 4; ++r) {
      const size_t orow = row0 + r;
      float v0 = fmaxf(acc0[r] + bv0, 0.0f);
      float v1 = fmaxf(acc1[r] + bv1, 0.0f);
      if (h8) {
        int q0 = __builtin_amdgcn_cvt_pk_fp8_f32(v0, v0, 0, false);
        int q1 = __builtin_amdgcn_cvt_pk_fp8_f32(v1, v1, 0, false);
        h8[orow * CD + c0]      = (unsigned char)q0;
        h8[orow * CD + c0 + 16] = (unsigned char)q1;
      }
      if (pooled) {
        if (fast) {
          p0 += v0; p1 += v1;
        } else {
          int g = sB[rt * 16 + quad * 4 + r];
          if (g >= 0) {
            atomicAdd(&pooled[g * CD + c0], v0);
            atomicAdd(&pooled[g * CD + c0 + 16], v1);
          }
        }
      }
    }
  }

  if (!pooled) return;

  if (fast) {   // butterfly column-reduce across quads, one atomic pair per col
    p0 += __shfl_xor(p0, 16, 64);
    p0 += __shfl_xor(p0, 32, 64);
    p1 += __shfl_xor(p1, 16, 64);
    p1 += __shfl_xor(p1, 32, 64);
    if (quad == 0) {
      const int g = sB[0];
      atomicAdd(&pooled[g * CD + c0], p0);
      atomicAdd(&pooled[g * CD + c0 + 16], p1);
    }
  }

  // ---- fused classifier: last block to retire computes out[g] ----
  __threadfence();   // release: my pooled atomics visible before counter bump
  if (tid == 0) {
    int prev = __hip_atomic_fetch_add(done, 1, __ATOMIC_ACQ_REL,
                                      __HIP_MEMORY_SCOPE_AGENT);
    slast = (prev == GGRID - 1) ? 1 : 0;
  }
  __syncthreads();
  if (slast) {
    const int wv = tid >> 6, ln = tid & 63;
    for (int g = wv; g < NG; g += 4) {
      float a0 = __hip_atomic_load(&pooled[g * CD + ln],
                                   __ATOMIC_RELAXED, __HIP_MEMORY_SCOPE_AGENT);
      float a1 = __hip_atomic_load(&pooled[g * CD + 64 + ln],
                                   __ATOMIC_RELAXED, __HIP_MEMORY_SCOPE_AGENT);
      float part = a0 * Wc[ln] + a1 * Wc[64 + ln];
#pragma unroll
      for (int off = 32; off > 0; off >>= 1) part += __shfl_down(part, off, 64);
      if (ln == 0) {
        float cnt = (float)(gb[g + 1] - gb[g]);
        float z = part / fmaxf(cnt, 1.0f) + bc[0];
        out[g] = 1.0f / (1.0f + expf(-z));
      }
    }
  }
}

extern "C" void kernel_launch(void* const* d_in, const int* in_sizes, int n_in,
                              void* d_out, int out_size, void* d_ws, size_t ws_size,
                              hipStream_t stream) {
  const float* x   = (const float*)d_in[0];
  const int*   ei  = (const int*)d_in[1];
  const int*   src = ei;             // edge_index[0]
  const int*   dst = ei + NED;       // edge_index[1]
  // d_in[2] = edge_weight: unused by the reference
  const int*   batch = (const int*)d_in[3];
  const float* Wc = (const float*)d_in[16];
  const float* bc = (const float*)d_in[17];
  float* out = (float*)d_out;

  char* w = (char*)d_ws;
  auto alloc = [&](size_t bytes) {
    char* p = w; w += (bytes + 255) & ~(size_t)255; return p;
  };
  // cnti + pooled + done first and contiguous: one memset covers all three
  int* cnti = (int*)alloc(NND * 4);
  float* pooled = (float*)alloc(NG * CD * 4);
  int* done = (int*)alloc(4);
  size_t zspan = (size_t)(w - (char*)cnti);
  int* offs = (int*)alloc((NND + 1) * 4);
  int* cur  = (int*)alloc(NND * 4);
  int* csr  = (int*)alloc((size_t)NED * 4);
  int* gb   = (int*)alloc((NG + 1) * 4);
  int* bsum = (int*)alloc(256 * 4);
  int* boff = (int*)alloc(256 * 4);
  unsigned char* x8a = (unsigned char*)alloc((size_t)LNP * CD);
  unsigned char* x8b = (unsigned char*)alloc((size_t)LNP * CD);
  WPtrs wp;
  for (int i = 0; i < 4; ++i) {
    wp.w[2 * i]     = (const float*)d_in[4 + 3 * i];      // Wl{i+1}
    wp.w[2 * i + 1] = (const float*)d_in[5 + 3 * i];      // Wr{i+1}
  }
  for (int i = 0; i < 8; ++i) wp.wt[i] = (unsigned short*)alloc(CD * CD * 2);
  const float* bs[4] = {(const float*)d_in[6],  (const float*)d_in[9],
                        (const float*)d_in[12], (const float*)d_in[15]};

  hipMemsetAsync(cnti, 0, zspan, stream);

  // preamble: fp8 convert + weight transposes + degree count in ONE kernel
  prep_k<<<(NND * 32 + 8 * CD * CD + NED + 255) / 256, 256, 0, stream>>>(
      x, (unsigned*)x8a, wp, dst, cnti);

  // CSR build (per call; inputs are restored before every timed launch)
  bsum_k<<<NBLK, 256, 0, stream>>>(cnti, bsum);
  bscan_k<<<1, 256, 0, stream>>>(bsum, boff, offs, batch, gb);
  escan_k<<<NBLK, 256, 0, stream>>>(cnti, boff, offs, cur);
  fill_k<<<(NED + 255) / 256, 256, 0, stream>>>(src, dst, cur, csr);

  unsigned char* qcur = x8a;
  unsigned char* qnxt = x8b;
  for (int l = 0; l < 4; ++l) {
    if (l < 3) {
      sage_k<<<GGRID, 256, 0, stream>>>((const unsigned*)qcur, csr, offs,
                                        wp.wt[2 * l], wp.wt[2 * l + 1], bs[l],
                                        qnxt, batch, nullptr,
                                        done, gb, Wc, bc, out);
      unsigned char* q = qcur; qcur = qnxt; qnxt = q;
    } else {
      // last layer: no feature output — pooling + classifier fused in epilogue
      sage_k<<<GGRID, 256, 0, stream>>>((const unsigned*)qcur, csr, offs,
                                        wp.wt[2 * l], wp.wt[2 * l + 1], bs[l],
                                        nullptr, batch, pooled,
                                        done, gb, Wc, bc, out);
    }
  }
}